// Round 5
// baseline (1426.808 us; speedup 1.0000x reference)
//
#include <hip/hip_runtime.h>

#define LAYERS 6
#define DIM    768
#define D3     2304
#define DF     3072
#define TT     2048
#define VOCAB  32000

typedef unsigned short u16;
typedef __attribute__((ext_vector_type(4))) float f32x4;
typedef __attribute__((ext_vector_type(8))) short s16x8;
typedef __attribute__((ext_vector_type(4))) unsigned short u16x4;

__device__ __forceinline__ float bf2f(u16 a){
  unsigned int u = ((unsigned int)a) << 16;
  float f; __builtin_memcpy(&f, &u, 4); return f;
}
__device__ __forceinline__ u16 f2bf(float f){
  unsigned int u; __builtin_memcpy(&u, &f, 4);
  u = (u + 0x7fffu + ((u >> 16) & 1u)) >> 16;
  return (u16)u;
}
__device__ __forceinline__ void gload_lds16(const void* g, void* l){
  __builtin_amdgcn_global_load_lds(
      (const __attribute__((address_space(1))) unsigned int*)g,
      (__attribute__((address_space(3))) unsigned int*)l, 16, 0, 0);
}
__device__ __forceinline__ void mfma16(f32x4& d, s16x8 a, s16x8 b){
  asm("v_mfma_f32_16x16x32_bf16 %0, %1, %2, %0" : "+v"(d) : "v"(a), "v"(b));
}

// ---------- weight fp32 [R][C] -> bf16 [C][R] (B^T layout), 64x64 tiles, grid.z = layer ----------
__global__ __launch_bounds__(256) void k_transpose(const float* __restrict__ in,
                                                   u16* __restrict__ out, int R, int C){
  __shared__ float tile[64][65];
  size_t ls = (size_t)R * C;
  in  += ls * blockIdx.z;
  out += ls * blockIdx.z;
  int r0 = blockIdx.y * 64, c0 = blockIdx.x * 64;
  int t = threadIdx.x;
  int tr = t >> 4, tc = (t & 15) * 4;
  #pragma unroll
  for (int j = 0; j < 4; ++j){
    float4 v = *(const float4*)(in + (size_t)(r0 + tr + j*16) * C + c0 + tc);
    tile[tr + j*16][tc+0] = v.x; tile[tr + j*16][tc+1] = v.y;
    tile[tr + j*16][tc+2] = v.z; tile[tr + j*16][tc+3] = v.w;
  }
  __syncthreads();
  #pragma unroll
  for (int j = 0; j < 4; ++j){
    u16x4 o;
    #pragma unroll
    for (int i = 0; i < 4; ++i) o[i] = f2bf(tile[tc+i][tr + j*16]);
    *(u16x4*)(out + (size_t)(c0 + tr + j*16) * R + r0 + tc) = o;
  }
}

// ---------- fp32 -> bf16 elementwise (tok_emb for tied lm_head) ----------
__global__ __launch_bounds__(256) void k_convert(const float* __restrict__ in, u16* __restrict__ out){
  int i = blockIdx.x * 256 + threadIdx.x;
  float4 v = ((const float4*)in)[i];
  u16x4 o;
  o[0] = f2bf(v.x); o[1] = f2bf(v.y); o[2] = f2bf(v.z); o[3] = f2bf(v.w);
  ((u16x4*)out)[i] = o;
}

// ---------- token + positional embedding -> x fp32 ----------
__global__ __launch_bounds__(256) void k_embed(const int* __restrict__ idx, const float* __restrict__ te,
                                               const float* __restrict__ pe, float* __restrict__ x){
  int t = blockIdx.x;
  int id = idx[t];
  const float* a = te + (size_t)id * DIM;
  const float* p = pe + (size_t)(t & 1023) * DIM;
  float* o = x + (size_t)t * DIM;
  #pragma unroll
  for (int j = 0; j < 3; ++j){
    int d = j * 256 + threadIdx.x;
    o[d] = a[d] + p[d];
  }
}

// ---------- layernorm fp32 -> bf16, one wave per row ----------
__global__ __launch_bounds__(256) void k_ln(const float* __restrict__ x, const float* __restrict__ g,
                                            const float* __restrict__ bb, u16* __restrict__ out){
  int row = blockIdx.x * 4 + (threadIdx.x >> 6);
  int lane = threadIdx.x & 63;
  const float* xr = x + (size_t)row * DIM;
  float v[12], s = 0.f;
  #pragma unroll
  for (int j = 0; j < 12; ++j){ v[j] = xr[j*64 + lane]; s += v[j]; }
  #pragma unroll
  for (int o = 32; o; o >>= 1) s += __shfl_xor(s, o);
  float mu = s * (1.f/768.f);
  float vs = 0.f;
  #pragma unroll
  for (int j = 0; j < 12; ++j){ float d = v[j]-mu; vs += d*d; }
  #pragma unroll
  for (int o = 32; o; o >>= 1) vs += __shfl_xor(vs, o);
  float rs = rsqrtf(vs * (1.f/768.f) + 1e-5f);
  u16* orow = out + (size_t)row * DIM;
  #pragma unroll
  for (int j = 0; j < 12; ++j){
    int c = j*64 + lane;
    orow[c] = f2bf((v[j]-mu)*rs*g[c] + bb[c]);
  }
}

// ---------- GEMM: A[M=2048][K] bf16 row-major, BT[N][K] bf16, TMx128 tile, BK=32 ----------
// TM = 128 (wave tile 64x64) or 64 (wave tile 32x64, for small-N GEMMs -> 2x grid).
// TAG distinguishes call sites in rocprof. XCD swizzle + m-fastest grouping; XOR chunk-swizzle LDS.
// EPI: 0 = fp32 store (no bias); 1 = +bias -> bf16; 2 = +bias, gelu -> bf16; 3 = +bias, += fp32 resid
template<int EPI, int TM, int TAG>
__global__ __launch_bounds__(256) void k_gemm(const u16* __restrict__ A, const u16* __restrict__ BT,
                                              const float* __restrict__ bias, void* __restrict__ outp,
                                              int N, int K){
  constexpr int MI  = TM / 32;       // m-fragments per wave
  constexpr int MBC = TT / TM;       // m-blocks per n-panel
  __shared__ __align__(16) u16 Ab[2][TM][32];
  __shared__ __align__(16) u16 Bb[2][128][32];
  int t = threadIdx.x, w = t >> 6, l = t & 63;
  // XCD swizzle: each XCD gets a contiguous wgid chunk; within chunk m varies fastest.
  int cpx = gridDim.x >> 3;               // all grids divisible by 8
  int wgid = (blockIdx.x & 7) * cpx + (blockIdx.x >> 3);
  int m0 = (wgid & (MBC - 1)) * TM;
  int n0 = (wgid / MBC) * 128;
  const u16* Ag = A  + (size_t)m0 * K;
  const u16* Bg = BT + (size_t)n0 * K;
  f32x4 acc[MI][4] = {};
  int NT = K >> 5;
  int lr = l >> 2;                            // staging row within 16-row group
  int cs = (((l & 3) ^ ((l >> 3) & 3)) * 8);  // swizzled source chunk (within 64B line)

  auto stage = [&](int buf, int kt){
    int k0 = kt * 32 + cs;
    int rb = w * 16;
    gload_lds16(Ag + (size_t)(rb + lr) * K + k0,      &Ab[buf][rb][0]);
    if constexpr (TM == 128)
      gload_lds16(Ag + (size_t)(64 + rb + lr) * K + k0, &Ab[buf][64 + rb][0]);
    gload_lds16(Bg + (size_t)(rb + lr) * K + k0,      &Bb[buf][rb][0]);
    gload_lds16(Bg + (size_t)(64 + rb + lr) * K + k0, &Bb[buf][64 + rb][0]);
  };

  stage(0, 0);
  __syncthreads();
  int wm = (w >> 1) * (TM / 2), wn = (w & 1) * 64;
  int ku = l >> 4, r16 = l & 15;
  int sl = (ku ^ ((r16 >> 1) & 3)) * 8;       // swizzled read slot (per-lane constant)
  for (int kt = 0; kt < NT; ++kt){
    int buf = kt & 1;
    if (kt + 1 < NT) stage(buf ^ 1, kt + 1);
    s16x8 af[MI], bfr[4];
    #pragma unroll
    for (int mi = 0; mi < MI; ++mi) af[mi]  = *(const s16x8*)&Ab[buf][wm + mi*16 + r16][sl];
    #pragma unroll
    for (int ni = 0; ni < 4; ++ni)  bfr[ni] = *(const s16x8*)&Bb[buf][wn + ni*16 + r16][sl];
    #pragma unroll
    for (int mi = 0; mi < MI; ++mi)
      #pragma unroll
      for (int ni = 0; ni < 4; ++ni)
        mfma16(acc[mi][ni], af[mi], bfr[ni]);
    __syncthreads();
  }
  asm volatile("s_nop 7\ns_nop 7\ns_nop 7\ns_nop 7");   // MFMA -> VALU hazard
  int rg = l >> 4;
  #pragma unroll
  for (int mi = 0; mi < MI; ++mi){
    #pragma unroll
    for (int ni = 0; ni < 4; ++ni){
      int col = n0 + wn + ni*16 + r16;
      float bv = (EPI != 0) ? bias[col] : 0.f;
      #pragma unroll
      for (int r = 0; r < 4; ++r){
        int row = m0 + wm + mi*16 + rg*4 + r;
        float v = acc[mi][ni][r] + bv;
        size_t oi = (size_t)row * N + col;
        if (EPI == 0)      ((float*)outp)[oi] = v;
        else if (EPI == 1) ((u16*)outp)[oi] = f2bf(v);
        else if (EPI == 2){ v = 0.5f*v*(1.f + erff(v*0.70710678118f)); ((u16*)outp)[oi] = f2bf(v); }
        else { float* p = (float*)outp + oi; *p += v; }
      }
    }
  }
}

// ---------- LM-head GEMM: BM=256, BN=128, BK=64, 8 waves, ring-3 LDS, counted vmcnt ----------
// Wave tile 64x64 (waves 4M x 2N). LDS chunk-swizzle: phys 16B-chunk = logical ^ (row&7);
// staging pre-swizzles the global source within each 128B row (gload_lds dest stays linear).
// Counted s_waitcnt vmcnt(6): stage K-tile t+2 while computing t -> ~2 iters of latency cover.
__global__ __launch_bounds__(512) void k_gemm256(const u16* __restrict__ A, const u16* __restrict__ BT,
                                                 float* __restrict__ outp, int N, int K){
  __shared__ __align__(16) u16 As[3][256][64];   // 96 KB
  __shared__ __align__(16) u16 Bs[3][128][64];   // 48 KB
  int t = threadIdx.x, w = t >> 6, l = t & 63;
  int cpx = gridDim.x >> 3;
  int wgid = (blockIdx.x & 7) * cpx + (blockIdx.x >> 3);
  int m0 = (wgid & 7) * 256;                 // M/256 == 8 (M = 2048)
  int n0 = (wgid >> 3) * 128;
  const u16* Ag = A  + (size_t)m0 * K;
  const u16* Bg = BT + (size_t)n0 * K;
  int KT = K >> 6;

  int srow = w * 8 + (l >> 3);               // row within a 64-row staging sweep
  int srcc = ((l & 7) ^ (l >> 3)) * 8;       // pre-swizzled source chunk (within 128B row)
  auto stage = [&](int kt, int slot){
    int k0 = kt * 64 + srcc;
    #pragma unroll
    for (int s = 0; s < 4; ++s)
      gload_lds16(Ag + (size_t)(s*64 + srow) * K + k0, &As[slot][s*64 + w*8][0]);
    #pragma unroll
    for (int s = 0; s < 2; ++s)
      gload_lds16(Bg + (size_t)(s*64 + srow) * K + k0, &Bs[slot][s*64 + w*8][0]);
  };

  f32x4 acc[4][4] = {};
  int wmi = w >> 1, wni = w & 1;             // 4 M-waves x 2 N-waves
  int r16 = l & 15, ku = l >> 4;
  int sw0 = ((ku)     ^ (r16 & 7)) * 8;      // swizzled read chunk, k-sub 0
  int sw1 = ((4 + ku) ^ (r16 & 7)) * 8;      // swizzled read chunk, k-sub 1

  // prologue: tiles 0 and 1 in flight; wait tile 0 (6 newest stay outstanding)
  stage(0, 0);
  stage(1, 1);
  asm volatile("s_waitcnt vmcnt(6)" ::: "memory");
  __builtin_amdgcn_s_barrier();
  __builtin_amdgcn_sched_barrier(0);

  int sr = 0;                                 // read slot = kt % 3
  for (int kt = 0; kt < KT; ++kt){
    bool more = (kt + 2) < KT;
    if (more){
      int ss = sr + 2; if (ss >= 3) ss -= 3;
      stage(kt + 2, ss);
    }
    s16x8 a0[4], a1[4], b0[4], b1[4];
    #pragma unroll
    for (int mf = 0; mf < 4; ++mf){
      a0[mf] = *(const s16x8*)&As[sr][wmi*64 + mf*16 + r16][sw0];
      a1[mf] = *(const s16x8*)&As[sr][wmi*64 + mf*16 + r16][sw1];
    }
    #pragma unroll
    for (int nf = 0; nf < 4; ++nf){
      b0[nf] = *(const s16x8*)&Bs[sr][wni*64 + nf*16 + r16][sw0];
      b1[nf] = *(const s16x8*)&Bs[sr][wni*64 + nf*16 + r16][sw1];
    }
    #pragma unroll
    for (int mf = 0; mf < 4; ++mf)
      #pragma unroll
      for (int nf = 0; nf < 4; ++nf){
        mfma16(acc[mf][nf], a0[mf], b0[nf]);
        mfma16(acc[mf][nf], a1[mf], b1[nf]);
      }
    if (more) asm volatile("s_waitcnt vmcnt(6) lgkmcnt(0)" ::: "memory");
    else      asm volatile("s_waitcnt vmcnt(0) lgkmcnt(0)" ::: "memory");
    __builtin_amdgcn_s_barrier();
    __builtin_amdgcn_sched_barrier(0);
    sr = (sr == 2) ? 0 : sr + 1;
  }
  asm volatile("s_nop 7\ns_nop 7\ns_nop 7\ns_nop 7");   // MFMA -> VALU hazard
  #pragma unroll
  for (int mf = 0; mf < 4; ++mf){
    #pragma unroll
    for (int nf = 0; nf < 4; ++nf){
      int col = n0 + wni*64 + nf*16 + r16;
      #pragma unroll
      for (int r = 0; r < 4; ++r){
        int row = m0 + wmi*64 + mf*16 + ku*4 + r;
        outp[(size_t)row * N + col] = acc[mf][nf][r];
      }
    }
  }
}

// ---------- V transpose: qkv V-slice -> VT[b][h][64 d][1024 s] bf16 ----------
__global__ __launch_bounds__(256) void k_vt(const u16* __restrict__ qkv, u16* __restrict__ vt){
  int st = blockIdx.x * 64, h = blockIdx.y, b = blockIdx.z;
  __shared__ u16 tile[64][72];
  int t = threadIdx.x;
  int r = t >> 2, cg = (t & 3) * 16;
  const u16* src = qkv + (size_t)(b*1024 + st + r) * D3 + 2*DIM + h*64 + cg;
  *(s16x8*)&tile[r][cg]   = *(const s16x8*)src;
  *(s16x8*)&tile[r][cg+8] = *(const s16x8*)(src + 8);
  __syncthreads();
  s16x8 o0, o1;
  #pragma unroll
  for (int j = 0; j < 8; ++j){ o0[j] = (short)tile[cg+j][r]; o1[j] = (short)tile[cg+8+j][r]; }
  u16* dst = vt + ((size_t)(b*12 + h)*64 + r)*1024 + st + cg;
  *(s16x8*)dst     = o0;
  *(s16x8*)(dst+8) = o1;
}

// ---------- flash attention, MFMA 16x16x32; block = 64 q rows (4 waves x 16) ----------
__global__ __launch_bounds__(256) void k_attn(const u16* __restrict__ qkv, const u16* __restrict__ vt,
                                              u16* __restrict__ y){
  int qb = blockIdx.x, h = blockIdx.y, b = blockIdx.z;
  int t = threadIdx.x, wv = t >> 6, l = t & 63;
  int q0 = qb * 64;
  __shared__ __align__(16) u16 Kt[64][72];   // [k][d], +8 pad breaks bank conflicts
  __shared__ __align__(16) u16 Vtl[64][72];  // [d][k]
  __shared__ __align__(16) u16 Pl[4][16][72];
  int colb = l & 15, rowg = (l >> 4) * 4;
  // Q fragments (registers, constant across tiles)
  const u16* qp = qkv + (size_t)(b*1024 + q0 + wv*16 + colb) * D3 + h*64 + (l>>4)*8;
  s16x8 qa0 = *(const s16x8*)qp;
  s16x8 qa1 = *(const s16x8*)(qp + 32);
  f32x4 ao[4] = {};
  float m[4]  = {-1e30f,-1e30f,-1e30f,-1e30f};
  float ls[4] = {0.f,0.f,0.f,0.f};
  const u16* kbase = qkv + (size_t)b*1024*D3 + DIM + h*64;
  const u16* vbase = vt + (size_t)(b*12 + h)*64*1024;
  int kk = t >> 2, cg = (t & 3) * 16;
  int ntiles = qb + 1;
  for (int kt = 0; kt < ntiles; ++kt){
    { // stage K tile [k][d] and V^T tile [d][k]
      const u16* ks = kbase + (size_t)(kt*64 + kk) * D3 + cg;
      *(s16x8*)&Kt[kk][cg]    = *(const s16x8*)ks;
      *(s16x8*)&Kt[kk][cg+8]  = *(const s16x8*)(ks + 8);
      const u16* vs = vbase + (size_t)kk * 1024 + kt*64 + cg;
      *(s16x8*)&Vtl[kk][cg]   = *(const s16x8*)vs;
      *(s16x8*)&Vtl[kk][cg+8] = *(const s16x8*)(vs + 8);
    }
    __syncthreads();
    // QK^T
    f32x4 as[4];
    #pragma unroll
    for (int nf = 0; nf < 4; ++nf){
      as[nf] = 0.f;
      s16x8 b0 = *(const s16x8*)&Kt[nf*16 + colb][(l>>4)*8];
      s16x8 b1 = *(const s16x8*)&Kt[nf*16 + colb][32 + (l>>4)*8];
      mfma16(as[nf], qa0, b0);
      mfma16(as[nf], qa1, b1);
    }
    asm volatile("s_nop 7\ns_nop 7\ns_nop 7");   // MFMA -> VALU hazard
    // mask + online softmax (fp32)
    float sv[4][4];
    int qgb = q0 + wv*16 + rowg;
    #pragma unroll
    for (int nf = 0; nf < 4; ++nf){
      int kglob = kt*64 + nf*16 + colb;
      #pragma unroll
      for (int r = 0; r < 4; ++r){
        float s = as[nf][r] * 0.125f;
        sv[nf][r] = (kglob > qgb + r) ? -1e30f : s;
      }
    }
    float corr[4], rs[4];
    #pragma unroll
    for (int r = 0; r < 4; ++r){
      float v = fmaxf(fmaxf(sv[0][r], sv[1][r]), fmaxf(sv[2][r], sv[3][r]));
      v = fmaxf(v, __shfl_xor(v, 1)); v = fmaxf(v, __shfl_xor(v, 2));
      v = fmaxf(v, __shfl_xor(v, 4)); v = fmaxf(v, __shfl_xor(v, 8));
      float mn = fmaxf(m[r], v);
      corr[r] = __expf(m[r] - mn);
      m[r] = mn;
      rs[r] = 0.f;
    }
    #pragma unroll
    for (int nf = 0; nf < 4; ++nf){
      #pragma unroll
      for (int r = 0; r < 4; ++r){
        float p = __expf(sv[nf][r] - m[r]);
        rs[r] += p;
        Pl[wv][rowg + r][nf*16 + colb] = f2bf(p);
      }
    }
    #pragma unroll
    for (int r = 0; r < 4; ++r){
      float v = rs[r];
      v += __shfl_xor(v, 1); v += __shfl_xor(v, 2); v += __shfl_xor(v, 4); v += __shfl_xor(v, 8);
      ls[r] = ls[r]*corr[r] + v;
    }
    #pragma unroll
    for (int nf = 0; nf < 4; ++nf)
      #pragma unroll
      for (int r = 0; r < 4; ++r)
        ao[nf][r] *= corr[r];
    asm volatile("s_waitcnt lgkmcnt(0)" ::: "memory");   // P writes -> P reads (wave-local)
    // PV
    s16x8 pa0 = *(const s16x8*)&Pl[wv][colb][(l>>4)*8];
    s16x8 pa1 = *(const s16x8*)&Pl[wv][colb][32 + (l>>4)*8];
    #pragma unroll
    for (int nf = 0; nf < 4; ++nf){
      s16x8 v0 = *(const s16x8*)&Vtl[nf*16 + colb][(l>>4)*8];
      s16x8 v1 = *(const s16x8*)&Vtl[nf*16 + colb][32 + (l>>4)*8];
      mfma16(ao[nf], pa0, v0);
      mfma16(ao[nf], pa1, v1);
    }
    __syncthreads();
  }
  asm volatile("s_nop 7\ns_nop 7\ns_nop 7\ns_nop 7");
  #pragma unroll
  for (int nf = 0; nf < 4; ++nf){
    #pragma unroll
    for (int r = 0; r < 4; ++r){
      int qg = q0 + wv*16 + rowg + r;
      int d  = nf*16 + colb;
      y[(size_t)(b*1024 + qg)*DIM + h*64 + d] = f2bf(ao[nf][r] / ls[r]);
    }
  }
}

extern "C" void kernel_launch(void* const* d_in, const int* in_sizes, int n_in,
                              void* d_out, int out_size, void* d_ws, size_t ws_size,
                              hipStream_t stream){
  (void)in_sizes; (void)n_in; (void)out_size; (void)ws_size;
  const int*   idx     = (const int*)  d_in[0];
  const float* tok_emb = (const float*)d_in[1];
  const float* pos_emb = (const float*)d_in[2];
  const float* ln1_g   = (const float*)d_in[3];
  const float* ln1_b   = (const float*)d_in[4];
  const float* qkv_w   = (const float*)d_in[5];
  const float* qkv_b   = (const float*)d_in[6];
  const float* attn_w  = (const float*)d_in[7];
  const float* attn_b  = (const float*)d_in[8];
  const float* ln2_g   = (const float*)d_in[9];
  const float* ln2_b   = (const float*)d_in[10];
  const float* fc_w    = (const float*)d_in[11];
  const float* fc_b    = (const float*)d_in[12];
  const float* mlp_w   = (const float*)d_in[13];
  const float* mlp_b   = (const float*)d_in[14];
  const float* lnf_g   = (const float*)d_in[15];
  const float* lnf_b   = (const float*)d_in[16];

  char* ws = (char*)d_ws;
  size_t off = 0;
  auto take = [&](size_t bytes)->char*{
    char* p = ws + off; off += (bytes + 255) & ~(size_t)255; return p;
  };
  u16*   wqkvT = (u16*)  take((size_t)LAYERS*D3*DIM*2);
  u16*   wattT = (u16*)  take((size_t)LAYERS*DIM*DIM*2);
  u16*   wfcT  = (u16*)  take((size_t)LAYERS*DF*DIM*2);
  u16*   wmlpT = (u16*)  take((size_t)LAYERS*DIM*DF*2);
  u16*   embB  = (u16*)  take((size_t)VOCAB*DIM*2);
  float* x     = (float*)take((size_t)TT*DIM*4);
  u16*   hbuf  = (u16*)  take((size_t)TT*DIM*2);
  u16*   qkvb  = (u16*)  take((size_t)TT*D3*2);
  u16*   yb    = (u16*)  take((size_t)TT*DIM*2);
  u16*   fcb   = (u16*)  take((size_t)TT*DF*2);
  u16*   xfb   = (u16*)  take((size_t)TT*DIM*2);
  u16*   vtb   = (u16*)  take((size_t)2*12*64*1024*2);

  // weight prep (bf16 + B^T layout)
  k_transpose<<<dim3(D3/64,  DIM/64, LAYERS), 256, 0, stream>>>(qkv_w, wqkvT, DIM, D3);
  k_transpose<<<dim3(DIM/64, DIM/64, LAYERS), 256, 0, stream>>>(attn_w, wattT, DIM, DIM);
  k_transpose<<<dim3(DF/64,  DIM/64, LAYERS), 256, 0, stream>>>(fc_w,  wfcT,  DIM, DF);
  k_transpose<<<dim3(DIM/64, DF/64,  LAYERS), 256, 0, stream>>>(mlp_w, wmlpT, DF, DIM);
  k_convert<<<(VOCAB*DIM)/1024, 256, 0, stream>>>(tok_emb, embB);

  k_embed<<<TT, 256, 0, stream>>>(idx, tok_emb, pos_emb, x);

  for (int l = 0; l < LAYERS; ++l){
    k_ln<<<TT/4, 256, 0, stream>>>(x, ln1_g + l*DIM, ln1_b + l*DIM, hbuf);
    k_gemm<1,128,0><<<dim3((TT/128)*(D3/128)), 256, 0, stream>>>(
        hbuf, wqkvT + (size_t)l*D3*DIM, qkv_b + l*D3, qkvb, D3, DIM);
    k_vt<<<dim3(16, 12, 2), 256, 0, stream>>>(qkvb, vtb);
    k_attn<<<dim3(16, 12, 2), 256, 0, stream>>>(qkvb, vtb, yb);
    k_gemm<3,64,1><<<dim3((TT/64)*(DIM/128)), 256, 0, stream>>>(
        yb, wattT + (size_t)l*DIM*DIM, attn_b + l*DIM, x, DIM, DIM);
    k_ln<<<TT/4, 256, 0, stream>>>(x, ln2_g + l*DIM, ln2_b + l*DIM, hbuf);
    k_gemm<2,128,2><<<dim3((TT/128)*(DF/128)), 256, 0, stream>>>(
        hbuf, wfcT + (size_t)l*DF*DIM, fc_b + l*DF, fcb, DF, DIM);
    k_gemm<3,64,3><<<dim3((TT/64)*(DIM/128)), 256, 0, stream>>>(
        fcb, wmlpT + (size_t)l*DIM*DF, mlp_b + l*DIM, x, DIM, DF);
  }
  k_ln<<<TT/4, 256, 0, stream>>>(x, lnf_g, lnf_b, xfb);
  k_gemm256<<<dim3((TT/256)*(VOCAB/128)), 512, 0, stream>>>(
      xfb, embB, (float*)d_out, VOCAB, DIM);
}

// Round 6
// 1421.920 us; speedup vs baseline: 1.0034x; 1.0034x over previous
//
#include <hip/hip_runtime.h>

#define LAYERS 6
#define DIM    768
#define D3     2304
#define DF     3072
#define TT     2048
#define VOCAB  32000

typedef unsigned short u16;
typedef __attribute__((ext_vector_type(4))) float f32x4;
typedef __attribute__((ext_vector_type(8))) short s16x8;
typedef __attribute__((ext_vector_type(4))) unsigned short u16x4;

__device__ __forceinline__ float bf2f(u16 a){
  unsigned int u = ((unsigned int)a) << 16;
  float f; __builtin_memcpy(&f, &u, 4); return f;
}
__device__ __forceinline__ u16 f2bf(float f){
  unsigned int u; __builtin_memcpy(&u, &f, 4);
  u = (u + 0x7fffu + ((u >> 16) & 1u)) >> 16;
  return (u16)u;
}
__device__ __forceinline__ void gload_lds16(const void* g, void* l){
  __builtin_amdgcn_global_load_lds(
      (const __attribute__((address_space(1))) unsigned int*)g,
      (__attribute__((address_space(3))) unsigned int*)l, 16, 0, 0);
}
__device__ __forceinline__ void mfma16(f32x4& d, s16x8 a, s16x8 b){
  asm("v_mfma_f32_16x16x32_bf16 %0, %1, %2, %0" : "+v"(d) : "v"(a), "v"(b));
}

// ---------- weight fp32 [R][C] -> bf16 [C][R] (B^T layout), 64x64 tiles, grid.z = layer ----------
__global__ __launch_bounds__(256) void k_transpose(const float* __restrict__ in,
                                                   u16* __restrict__ out, int R, int C){
  __shared__ float tile[64][65];
  size_t ls = (size_t)R * C;
  in  += ls * blockIdx.z;
  out += ls * blockIdx.z;
  int r0 = blockIdx.y * 64, c0 = blockIdx.x * 64;
  int t = threadIdx.x;
  int tr = t >> 4, tc = (t & 15) * 4;
  #pragma unroll
  for (int j = 0; j < 4; ++j){
    float4 v = *(const float4*)(in + (size_t)(r0 + tr + j*16) * C + c0 + tc);
    tile[tr + j*16][tc+0] = v.x; tile[tr + j*16][tc+1] = v.y;
    tile[tr + j*16][tc+2] = v.z; tile[tr + j*16][tc+3] = v.w;
  }
  __syncthreads();
  #pragma unroll
  for (int j = 0; j < 4; ++j){
    u16x4 o;
    #pragma unroll
    for (int i = 0; i < 4; ++i) o[i] = f2bf(tile[tc+i][tr + j*16]);
    *(u16x4*)(out + (size_t)(c0 + tr + j*16) * R + r0 + tc) = o;
  }
}

// ---------- fp32 -> bf16 elementwise (tok_emb for tied lm_head) ----------
__global__ __launch_bounds__(256) void k_convert(const float* __restrict__ in, u16* __restrict__ out){
  int i = blockIdx.x * 256 + threadIdx.x;
  float4 v = ((const float4*)in)[i];
  u16x4 o;
  o[0] = f2bf(v.x); o[1] = f2bf(v.y); o[2] = f2bf(v.z); o[3] = f2bf(v.w);
  ((u16x4*)out)[i] = o;
}

// ---------- token + positional embedding -> x fp32 ----------
__global__ __launch_bounds__(256) void k_embed(const int* __restrict__ idx, const float* __restrict__ te,
                                               const float* __restrict__ pe, float* __restrict__ x){
  int t = blockIdx.x;
  int id = idx[t];
  const float* a = te + (size_t)id * DIM;
  const float* p = pe + (size_t)(t & 1023) * DIM;
  float* o = x + (size_t)t * DIM;
  #pragma unroll
  for (int j = 0; j < 3; ++j){
    int d = j * 256 + threadIdx.x;
    o[d] = a[d] + p[d];
  }
}

// ---------- layernorm fp32 -> bf16, one wave per row ----------
__global__ __launch_bounds__(256) void k_ln(const float* __restrict__ x, const float* __restrict__ g,
                                            const float* __restrict__ bb, u16* __restrict__ out){
  int row = blockIdx.x * 4 + (threadIdx.x >> 6);
  int lane = threadIdx.x & 63;
  const float* xr = x + (size_t)row * DIM;
  float v[12], s = 0.f;
  #pragma unroll
  for (int j = 0; j < 12; ++j){ v[j] = xr[j*64 + lane]; s += v[j]; }
  #pragma unroll
  for (int o = 32; o; o >>= 1) s += __shfl_xor(s, o);
  float mu = s * (1.f/768.f);
  float vs = 0.f;
  #pragma unroll
  for (int j = 0; j < 12; ++j){ float d = v[j]-mu; vs += d*d; }
  #pragma unroll
  for (int o = 32; o; o >>= 1) vs += __shfl_xor(vs, o);
  float rs = rsqrtf(vs * (1.f/768.f) + 1e-5f);
  u16* orow = out + (size_t)row * DIM;
  #pragma unroll
  for (int j = 0; j < 12; ++j){
    int c = j*64 + lane;
    orow[c] = f2bf((v[j]-mu)*rs*g[c] + bb[c]);
  }
}

// ---------- GEMM: A[M=2048][K] bf16 row-major, BT[N][K] bf16, TMx128 tile, BK=32 ----------
// TM = 128 (wave tile 64x64) or 64 (wave tile 32x64, for small-N GEMMs -> 2x grid).
// TAG distinguishes call sites in rocprof. XCD swizzle + m-fastest grouping; XOR chunk-swizzle LDS.
// EPI: 0 = fp32 store (no bias); 1 = +bias -> bf16; 2 = +bias, gelu -> bf16; 3 = +bias, += fp32 resid
template<int EPI, int TM, int TAG>
__global__ __launch_bounds__(256) void k_gemm(const u16* __restrict__ A, const u16* __restrict__ BT,
                                              const float* __restrict__ bias, void* __restrict__ outp,
                                              int N, int K){
  constexpr int MI  = TM / 32;       // m-fragments per wave
  constexpr int MBC = TT / TM;       // m-blocks per n-panel
  __shared__ __align__(16) u16 Ab[2][TM][32];
  __shared__ __align__(16) u16 Bb[2][128][32];
  int t = threadIdx.x, w = t >> 6, l = t & 63;
  // XCD swizzle: each XCD gets a contiguous wgid chunk; within chunk m varies fastest.
  int cpx = gridDim.x >> 3;               // all grids divisible by 8
  int wgid = (blockIdx.x & 7) * cpx + (blockIdx.x >> 3);
  int m0 = (wgid & (MBC - 1)) * TM;
  int n0 = (wgid / MBC) * 128;
  const u16* Ag = A  + (size_t)m0 * K;
  const u16* Bg = BT + (size_t)n0 * K;
  f32x4 acc[MI][4] = {};
  int NT = K >> 5;
  int lr = l >> 2;                            // staging row within 16-row group
  int cs = (((l & 3) ^ ((l >> 3) & 3)) * 8);  // swizzled source chunk (within 64B line)

  auto stage = [&](int buf, int kt){
    int k0 = kt * 32 + cs;
    int rb = w * 16;
    gload_lds16(Ag + (size_t)(rb + lr) * K + k0,      &Ab[buf][rb][0]);
    if constexpr (TM == 128)
      gload_lds16(Ag + (size_t)(64 + rb + lr) * K + k0, &Ab[buf][64 + rb][0]);
    gload_lds16(Bg + (size_t)(rb + lr) * K + k0,      &Bb[buf][rb][0]);
    gload_lds16(Bg + (size_t)(64 + rb + lr) * K + k0, &Bb[buf][64 + rb][0]);
  };

  stage(0, 0);
  __syncthreads();
  int wm = (w >> 1) * (TM / 2), wn = (w & 1) * 64;
  int ku = l >> 4, r16 = l & 15;
  int sl = (ku ^ ((r16 >> 1) & 3)) * 8;       // swizzled read slot (per-lane constant)
  for (int kt = 0; kt < NT; ++kt){
    int buf = kt & 1;
    if (kt + 1 < NT) stage(buf ^ 1, kt + 1);
    s16x8 af[MI], bfr[4];
    #pragma unroll
    for (int mi = 0; mi < MI; ++mi) af[mi]  = *(const s16x8*)&Ab[buf][wm + mi*16 + r16][sl];
    #pragma unroll
    for (int ni = 0; ni < 4; ++ni)  bfr[ni] = *(const s16x8*)&Bb[buf][wn + ni*16 + r16][sl];
    #pragma unroll
    for (int mi = 0; mi < MI; ++mi)
      #pragma unroll
      for (int ni = 0; ni < 4; ++ni)
        mfma16(acc[mi][ni], af[mi], bfr[ni]);
    __syncthreads();
  }
  asm volatile("s_nop 7\ns_nop 7\ns_nop 7\ns_nop 7");   // MFMA -> VALU hazard
  int rg = l >> 4;
  #pragma unroll
  for (int mi = 0; mi < MI; ++mi){
    #pragma unroll
    for (int ni = 0; ni < 4; ++ni){
      int col = n0 + wn + ni*16 + r16;
      float bv = (EPI != 0) ? bias[col] : 0.f;
      #pragma unroll
      for (int r = 0; r < 4; ++r){
        int row = m0 + wm + mi*16 + rg*4 + r;
        float v = acc[mi][ni][r] + bv;
        size_t oi = (size_t)row * N + col;
        if (EPI == 0)      ((float*)outp)[oi] = v;
        else if (EPI == 1) ((u16*)outp)[oi] = f2bf(v);
        else if (EPI == 2){ v = 0.5f*v*(1.f + erff(v*0.70710678118f)); ((u16*)outp)[oi] = f2bf(v); }
        else { float* p = (float*)outp + oi; *p += v; }
      }
    }
  }
}

// ---------- LM-head GEMM: BM=256, BN=128, BK=64, 8 waves, ring-3 LDS, fine 2-phase interleave ----------
// Per K-tile: 2 phases of {8x ds_read (one k-half) || 3x global_load_lds (half of tile t+2)
//   -> raw s_barrier -> setprio(1) -> 16 MFMA -> setprio(0) -> s_barrier}.
// vmcnt(6) once per K-tile (outstanding = t+1's 6 oldest + t+2's 6 newest); never 0 until tail.
// LDS chunk-swizzle: phys 16B-chunk = logical ^ (row&7); staging pre-swizzles global source.
__global__ __launch_bounds__(512) void k_gemm256(const u16* __restrict__ A, const u16* __restrict__ BT,
                                                 float* __restrict__ outp, int N, int K){
  __shared__ __align__(16) u16 As[3][256][64];   // 96 KB
  __shared__ __align__(16) u16 Bs[3][128][64];   // 48 KB
  int t = threadIdx.x, w = t >> 6, l = t & 63;
  int cpx = gridDim.x >> 3;
  int wgid = (blockIdx.x & 7) * cpx + (blockIdx.x >> 3);
  int m0 = (wgid & 7) * 256;                 // M/256 == 8 (M = 2048)
  int n0 = (wgid >> 3) * 128;
  const u16* Ag = A  + (size_t)m0 * K;
  const u16* Bg = BT + (size_t)n0 * K;
  int KT = K >> 6;                           // 12

  int srow = w * 8 + (l >> 3);               // staging row within a 64-row sweep
  int srcc = ((l & 7) ^ (l >> 3)) * 8;       // pre-swizzled source chunk (within 128B row)
  // half-stage P0: A rows 0..127 + B rows 0..63 (3 loads); P1: A 128..255 + B 64..127 (3 loads)
  auto stageP0 = [&](int kt, int slot){
    int k0 = kt * 64 + srcc;
    gload_lds16(Ag + (size_t)(srow) * K + k0,       &As[slot][w*8][0]);
    gload_lds16(Ag + (size_t)(64 + srow) * K + k0,  &As[slot][64 + w*8][0]);
    gload_lds16(Bg + (size_t)(srow) * K + k0,       &Bs[slot][w*8][0]);
  };
  auto stageP1 = [&](int kt, int slot){
    int k0 = kt * 64 + srcc;
    gload_lds16(Ag + (size_t)(128 + srow) * K + k0, &As[slot][128 + w*8][0]);
    gload_lds16(Ag + (size_t)(192 + srow) * K + k0, &As[slot][192 + w*8][0]);
    gload_lds16(Bg + (size_t)(64 + srow) * K + k0,  &Bs[slot][64 + w*8][0]);
  };

  f32x4 acc[4][4] = {};
  int wmi = w >> 1, wni = w & 1;             // 4 M-waves x 2 N-waves, wave tile 64x64
  int r16 = l & 15, ku = l >> 4;
  int sw0 = ((ku)     ^ (r16 & 7)) * 8;      // swizzled read chunk, k-sub 0
  int sw1 = ((4 + ku) ^ (r16 & 7)) * 8;      // swizzled read chunk, k-sub 1

  // prologue: tiles 0,1 fully issued (12 outstanding); retire tile 0 (6 newest remain)
  stageP0(0, 0); stageP1(0, 0);
  stageP0(1, 1); stageP1(1, 1);
  asm volatile("s_waitcnt vmcnt(6)" ::: "memory");
  __builtin_amdgcn_s_barrier();
  __builtin_amdgcn_sched_barrier(0);

  int sr = 0;                                 // read slot = kt % 3
  for (int kt = 0; kt < KT; ++kt){
    int ss = sr + 2; if (ss >= 3) ss -= 3;    // stage slot = (kt+2) % 3
    bool pre = (kt + 2) < KT;
    s16x8 a[4], b[4];
    // ---------- phase 0 (k-sub 0) ----------
    #pragma unroll
    for (int mf = 0; mf < 4; ++mf) a[mf] = *(const s16x8*)&As[sr][wmi*64 + mf*16 + r16][sw0];
    #pragma unroll
    for (int nf = 0; nf < 4; ++nf) b[nf] = *(const s16x8*)&Bs[sr][wni*64 + nf*16 + r16][sw0];
    if (pre) stageP0(kt + 2, ss);
    __builtin_amdgcn_sched_barrier(0);
    __builtin_amdgcn_s_barrier();
    __builtin_amdgcn_sched_barrier(0);
    __builtin_amdgcn_s_setprio(1);
    #pragma unroll
    for (int mf = 0; mf < 4; ++mf)
      #pragma unroll
      for (int nf = 0; nf < 4; ++nf)
        mfma16(acc[mf][nf], a[mf], b[nf]);
    __builtin_amdgcn_s_setprio(0);
    __builtin_amdgcn_sched_barrier(0);
    __builtin_amdgcn_s_barrier();
    __builtin_amdgcn_sched_barrier(0);
    // ---------- phase 1 (k-sub 1) ----------
    #pragma unroll
    for (int mf = 0; mf < 4; ++mf) a[mf] = *(const s16x8*)&As[sr][wmi*64 + mf*16 + r16][sw1];
    #pragma unroll
    for (int nf = 0; nf < 4; ++nf) b[nf] = *(const s16x8*)&Bs[sr][wni*64 + nf*16 + r16][sw1];
    if (pre) stageP1(kt + 2, ss);
    if (kt + 1 < KT){                          // gate for tile t+1 (read next iteration)
      if (pre) asm volatile("s_waitcnt vmcnt(6)" ::: "memory");
      else     asm volatile("s_waitcnt vmcnt(0)" ::: "memory");
    }
    __builtin_amdgcn_sched_barrier(0);
    __builtin_amdgcn_s_barrier();
    __builtin_amdgcn_sched_barrier(0);
    __builtin_amdgcn_s_setprio(1);
    #pragma unroll
    for (int mf = 0; mf < 4; ++mf)
      #pragma unroll
      for (int nf = 0; nf < 4; ++nf)
        mfma16(acc[mf][nf], a[mf], b[nf]);
    __builtin_amdgcn_s_setprio(0);
    __builtin_amdgcn_sched_barrier(0);
    __builtin_amdgcn_s_barrier();
    __builtin_amdgcn_sched_barrier(0);
    sr = sr + 1; if (sr == 3) sr = 0;
  }
  asm volatile("s_nop 7\ns_nop 7\ns_nop 7\ns_nop 7");   // MFMA -> VALU hazard
  #pragma unroll
  for (int mf = 0; mf < 4; ++mf){
    #pragma unroll
    for (int nf = 0; nf < 4; ++nf){
      int col = n0 + wni*64 + nf*16 + r16;
      #pragma unroll
      for (int r = 0; r < 4; ++r){
        int row = m0 + wmi*64 + mf*16 + ku*4 + r;
        outp[(size_t)row * N + col] = acc[mf][nf][r];
      }
    }
  }
}

// ---------- V transpose: qkv V-slice -> VT[b][h][64 d][1024 s] bf16 ----------
__global__ __launch_bounds__(256) void k_vt(const u16* __restrict__ qkv, u16* __restrict__ vt){
  int st = blockIdx.x * 64, h = blockIdx.y, b = blockIdx.z;
  __shared__ u16 tile[64][72];
  int t = threadIdx.x;
  int r = t >> 2, cg = (t & 3) * 16;
  const u16* src = qkv + (size_t)(b*1024 + st + r) * D3 + 2*DIM + h*64 + cg;
  *(s16x8*)&tile[r][cg]   = *(const s16x8*)src;
  *(s16x8*)&tile[r][cg+8] = *(const s16x8*)(src + 8);
  __syncthreads();
  s16x8 o0, o1;
  #pragma unroll
  for (int j = 0; j < 8; ++j){ o0[j] = (short)tile[cg+j][r]; o1[j] = (short)tile[cg+8+j][r]; }
  u16* dst = vt + ((size_t)(b*12 + h)*64 + r)*1024 + st + cg;
  *(s16x8*)dst     = o0;
  *(s16x8*)(dst+8) = o1;
}

// ---------- flash attention, MFMA 16x16x32; block = 64 q rows (4 waves x 16) ----------
__global__ __launch_bounds__(256) void k_attn(const u16* __restrict__ qkv, const u16* __restrict__ vt,
                                              u16* __restrict__ y){
  int qb = blockIdx.x, h = blockIdx.y, b = blockIdx.z;
  int t = threadIdx.x, wv = t >> 6, l = t & 63;
  int q0 = qb * 64;
  __shared__ __align__(16) u16 Kt[64][72];   // [k][d], +8 pad breaks bank conflicts
  __shared__ __align__(16) u16 Vtl[64][72];  // [d][k]
  __shared__ __align__(16) u16 Pl[4][16][72];
  int colb = l & 15, rowg = (l >> 4) * 4;
  // Q fragments (registers, constant across tiles)
  const u16* qp = qkv + (size_t)(b*1024 + q0 + wv*16 + colb) * D3 + h*64 + (l>>4)*8;
  s16x8 qa0 = *(const s16x8*)qp;
  s16x8 qa1 = *(const s16x8*)(qp + 32);
  f32x4 ao[4] = {};
  float m[4]  = {-1e30f,-1e30f,-1e30f,-1e30f};
  float ls[4] = {0.f,0.f,0.f,0.f};
  const u16* kbase = qkv + (size_t)b*1024*D3 + DIM + h*64;
  const u16* vbase = vt + (size_t)(b*12 + h)*64*1024;
  int kk = t >> 2, cg = (t & 3) * 16;
  int ntiles = qb + 1;
  for (int kt = 0; kt < ntiles; ++kt){
    { // stage K tile [k][d] and V^T tile [d][k]
      const u16* ks = kbase + (size_t)(kt*64 + kk) * D3 + cg;
      *(s16x8*)&Kt[kk][cg]    = *(const s16x8*)ks;
      *(s16x8*)&Kt[kk][cg+8]  = *(const s16x8*)(ks + 8);
      const u16* vs = vbase + (size_t)kk * 1024 + kt*64 + cg;
      *(s16x8*)&Vtl[kk][cg]   = *(const s16x8*)vs;
      *(s16x8*)&Vtl[kk][cg+8] = *(const s16x8*)(vs + 8);
    }
    __syncthreads();
    // QK^T
    f32x4 as[4];
    #pragma unroll
    for (int nf = 0; nf < 4; ++nf){
      as[nf] = 0.f;
      s16x8 b0 = *(const s16x8*)&Kt[nf*16 + colb][(l>>4)*8];
      s16x8 b1 = *(const s16x8*)&Kt[nf*16 + colb][32 + (l>>4)*8];
      mfma16(as[nf], qa0, b0);
      mfma16(as[nf], qa1, b1);
    }
    asm volatile("s_nop 7\ns_nop 7\ns_nop 7");   // MFMA -> VALU hazard
    // mask + online softmax (fp32)
    float sv[4][4];
    int qgb = q0 + wv*16 + rowg;
    #pragma unroll
    for (int nf = 0; nf < 4; ++nf){
      int kglob = kt*64 + nf*16 + colb;
      #pragma unroll
      for (int r = 0; r < 4; ++r){
        float s = as[nf][r] * 0.125f;
        sv[nf][r] = (kglob > qgb + r) ? -1e30f : s;
      }
    }
    float corr[4], rs[4];
    #pragma unroll
    for (int r = 0; r < 4; ++r){
      float v = fmaxf(fmaxf(sv[0][r], sv[1][r]), fmaxf(sv[2][r], sv[3][r]));
      v = fmaxf(v, __shfl_xor(v, 1)); v = fmaxf(v, __shfl_xor(v, 2));
      v = fmaxf(v, __shfl_xor(v, 4)); v = fmaxf(v, __shfl_xor(v, 8));
      float mn = fmaxf(m[r], v);
      corr[r] = __expf(m[r] - mn);
      m[r] = mn;
      rs[r] = 0.f;
    }
    #pragma unroll
    for (int nf = 0; nf < 4; ++nf){
      #pragma unroll
      for (int r = 0; r < 4; ++r){
        float p = __expf(sv[nf][r] - m[r]);
        rs[r] += p;
        Pl[wv][rowg + r][nf*16 + colb] = f2bf(p);
      }
    }
    #pragma unroll
    for (int r = 0; r < 4; ++r){
      float v = rs[r];
      v += __shfl_xor(v, 1); v += __shfl_xor(v, 2); v += __shfl_xor(v, 4); v += __shfl_xor(v, 8);
      ls[r] = ls[r]*corr[r] + v;
    }
    #pragma unroll
    for (int nf = 0; nf < 4; ++nf)
      #pragma unroll
      for (int r = 0; r < 4; ++r)
        ao[nf][r] *= corr[r];
    asm volatile("s_waitcnt lgkmcnt(0)" ::: "memory");   // P writes -> P reads (wave-local)
    // PV
    s16x8 pa0 = *(const s16x8*)&Pl[wv][colb][(l>>4)*8];
    s16x8 pa1 = *(const s16x8*)&Pl[wv][colb][32 + (l>>4)*8];
    #pragma unroll
    for (int nf = 0; nf < 4; ++nf){
      s16x8 v0 = *(const s16x8*)&Vtl[nf*16 + colb][(l>>4)*8];
      s16x8 v1 = *(const s16x8*)&Vtl[nf*16 + colb][32 + (l>>4)*8];
      mfma16(ao[nf], pa0, v0);
      mfma16(ao[nf], pa1, v1);
    }
    __syncthreads();
  }
  asm volatile("s_nop 7\ns_nop 7\ns_nop 7\ns_nop 7");
  #pragma unroll
  for (int nf = 0; nf < 4; ++nf){
    #pragma unroll
    for (int r = 0; r < 4; ++r){
      int qg = q0 + wv*16 + rowg + r;
      int d  = nf*16 + colb;
      y[(size_t)(b*1024 + qg)*DIM + h*64 + d] = f2bf(ao[nf][r] / ls[r]);
    }
  }
}

extern "C" void kernel_launch(void* const* d_in, const int* in_sizes, int n_in,
                              void* d_out, int out_size, void* d_ws, size_t ws_size,
                              hipStream_t stream){
  (void)in_sizes; (void)n_in; (void)out_size; (void)ws_size;
  const int*   idx     = (const int*)  d_in[0];
  const float* tok_emb = (const float*)d_in[1];
  const float* pos_emb = (const float*)d_in[2];
  const float* ln1_g   = (const float*)d_in[3];
  const float* ln1_b   = (const float*)d_in[4];
  const float* qkv_w   = (const float*)d_in[5];
  const float* qkv_b   = (const float*)d_in[6];
  const float* attn_w  = (const float*)d_in[7];
  const float* attn_b  = (const float*)d_in[8];
  const float* ln2_g   = (const float*)d_in[9];
  const float* ln2_b   = (const float*)d_in[10];
  const float* fc_w    = (const float*)d_in[11];
  const float* fc_b    = (const float*)d_in[12];
  const float* mlp_w   = (const float*)d_in[13];
  const float* mlp_b   = (const float*)d_in[14];
  const float* lnf_g   = (const float*)d_in[15];
  const float* lnf_b   = (const float*)d_in[16];

  char* ws = (char*)d_ws;
  size_t off = 0;
  auto take = [&](size_t bytes)->char*{
    char* p = ws + off; off += (bytes + 255) & ~(size_t)255; return p;
  };
  u16*   wqkvT = (u16*)  take((size_t)LAYERS*D3*DIM*2);
  u16*   wattT = (u16*)  take((size_t)LAYERS*DIM*DIM*2);
  u16*   wfcT  = (u16*)  take((size_t)LAYERS*DF*DIM*2);
  u16*   wmlpT = (u16*)  take((size_t)LAYERS*DIM*DF*2);
  u16*   embB  = (u16*)  take((size_t)VOCAB*DIM*2);
  float* x     = (float*)take((size_t)TT*DIM*4);
  u16*   hbuf  = (u16*)  take((size_t)TT*DIM*2);
  u16*   qkvb  = (u16*)  take((size_t)TT*D3*2);
  u16*   yb    = (u16*)  take((size_t)TT*DIM*2);
  u16*   fcb   = (u16*)  take((size_t)TT*DF*2);
  u16*   xfb   = (u16*)  take((size_t)TT*DIM*2);
  u16*   vtb   = (u16*)  take((size_t)2*12*64*1024*2);

  // weight prep (bf16 + B^T layout)
  k_transpose<<<dim3(D3/64,  DIM/64, LAYERS), 256, 0, stream>>>(qkv_w, wqkvT, DIM, D3);
  k_transpose<<<dim3(DIM/64, DIM/64, LAYERS), 256, 0, stream>>>(attn_w, wattT, DIM, DIM);
  k_transpose<<<dim3(DF/64,  DIM/64, LAYERS), 256, 0, stream>>>(fc_w,  wfcT,  DIM, DF);
  k_transpose<<<dim3(DIM/64, DF/64,  LAYERS), 256, 0, stream>>>(mlp_w, wmlpT, DF, DIM);
  k_convert<<<(VOCAB*DIM)/1024, 256, 0, stream>>>(tok_emb, embB);

  k_embed<<<TT, 256, 0, stream>>>(idx, tok_emb, pos_emb, x);

  for (int l = 0; l < LAYERS; ++l){
    k_ln<<<TT/4, 256, 0, stream>>>(x, ln1_g + l*DIM, ln1_b + l*DIM, hbuf);
    k_gemm<1,128,0><<<dim3((TT/128)*(D3/128)), 256, 0, stream>>>(
        hbuf, wqkvT + (size_t)l*D3*DIM, qkv_b + l*D3, qkvb, D3, DIM);
    k_vt<<<dim3(16, 12, 2), 256, 0, stream>>>(qkvb, vtb);
    k_attn<<<dim3(16, 12, 2), 256, 0, stream>>>(qkvb, vtb, yb);
    k_gemm<3,64,1><<<dim3((TT/64)*(DIM/128)), 256, 0, stream>>>(
        yb, wattT + (size_t)l*DIM*DIM, attn_b + l*DIM, x, DIM, DIM);
    k_ln<<<TT/4, 256, 0, stream>>>(x, ln2_g + l*DIM, ln2_b + l*DIM, hbuf);
    k_gemm<2,128,2><<<dim3((TT/128)*(DF/128)), 256, 0, stream>>>(
        hbuf, wfcT + (size_t)l*DF*DIM, fc_b + l*DF, fcb, DF, DIM);
    k_gemm<3,64,3><<<dim3((TT/64)*(DIM/128)), 256, 0, stream>>>(
        fcb, wmlpT + (size_t)l*DIM*DF, mlp_b + l*DIM, x, DIM, DF);
  }
  k_ln<<<TT/4, 256, 0, stream>>>(x, lnf_g, lnf_b, xfb);
  k_gemm256<<<dim3((TT/256)*(VOCAB/128)), 512, 0, stream>>>(
      xfb, embB, (float*)d_out, VOCAB, DIM);
}

// Round 8
// 1384.425 us; speedup vs baseline: 1.0306x; 1.0271x over previous
//
#include <hip/hip_runtime.h>

#define LAYERS 6
#define DIM    768
#define D3     2304
#define DF     3072
#define TT     2048
#define VOCAB  32000

typedef unsigned short u16;
typedef __attribute__((ext_vector_type(4))) float f32x4;
typedef __attribute__((ext_vector_type(8))) short s16x8;
typedef __attribute__((ext_vector_type(4))) unsigned short u16x4;

__device__ __forceinline__ float bf2f(u16 a){
  unsigned int u = ((unsigned int)a) << 16;
  float f; __builtin_memcpy(&f, &u, 4); return f;
}
__device__ __forceinline__ u16 f2bf(float f){
  unsigned int u; __builtin_memcpy(&u, &f, 4);
  u = (u + 0x7fffu + ((u >> 16) & 1u)) >> 16;
  return (u16)u;
}
__device__ __forceinline__ void gload_lds16(const void* g, void* l){
  __builtin_amdgcn_global_load_lds(
      (const __attribute__((address_space(1))) unsigned int*)g,
      (__attribute__((address_space(3))) unsigned int*)l, 16, 0, 0);
}
__device__ __forceinline__ void mfma16(f32x4& d, s16x8 a, s16x8 b){
  asm("v_mfma_f32_16x16x32_bf16 %0, %1, %2, %0" : "+v"(d) : "v"(a), "v"(b));
}

// ---------- merged weight prep: 4 transposes (fp32 [R][C] -> bf16 [C][R]) + tok_emb convert ----------
// segment layout (blocks): [0,2592) qkv_w | [2592,3456) attn_w | [3456,6912) fc_w
//                          | [6912,10368) mlp_w | [10368,16368) tok_emb convert (1024 f32x4/block)
__global__ __launch_bounds__(256) void k_prep(const float* __restrict__ qkv_w,
                                              const float* __restrict__ attn_w,
                                              const float* __restrict__ fc_w,
                                              const float* __restrict__ mlp_w,
                                              const float* __restrict__ tok_emb,
                                              u16* __restrict__ wqkvT, u16* __restrict__ wattT,
                                              u16* __restrict__ wfcT,  u16* __restrict__ wmlpT,
                                              u16* __restrict__ embB){
  int bid = blockIdx.x;
  if (bid >= 10368){            // tok_emb fp32 -> bf16, 1024 float4 per block (4 sweeps of 256)
    int base = (bid - 10368) * 1024;
    #pragma unroll
    for (int j = 0; j < 4; ++j){
      int i = base + j * 256 + threadIdx.x;
      float4 v = ((const float4*)tok_emb)[i];
      u16x4 o;
      o[0] = f2bf(v.x); o[1] = f2bf(v.y); o[2] = f2bf(v.z); o[3] = f2bf(v.w);
      ((u16x4*)embB)[i] = o;
    }
    return;
  }
  const float* in; u16* out; int R, C, tpl;
  if (bid < 2592)      {             in = qkv_w;  out = wqkvT; R = 768;  C = 2304; tpl = 432; }
  else if (bid < 3456) { bid -= 2592; in = attn_w; out = wattT; R = 768;  C = 768;  tpl = 144; }
  else if (bid < 6912) { bid -= 3456; in = fc_w;   out = wfcT;  R = 768;  C = 3072; tpl = 576; }
  else                 { bid -= 6912; in = mlp_w;  out = wmlpT; R = 3072; C = 768;  tpl = 576; }
  int layer = bid / tpl, rem = bid - layer * tpl;
  int cpt = C >> 6;
  int bx = rem % cpt, by = rem / cpt;
  size_t ls = (size_t)R * C;
  in  += ls * layer;
  out += ls * layer;
  __shared__ float tile[64][65];
  int r0 = by * 64, c0 = bx * 64;
  int t = threadIdx.x;
  int tr = t >> 4, tc = (t & 15) * 4;
  #pragma unroll
  for (int j = 0; j < 4; ++j){
    float4 v = *(const float4*)(in + (size_t)(r0 + tr + j*16) * C + c0 + tc);
    tile[tr + j*16][tc+0] = v.x; tile[tr + j*16][tc+1] = v.y;
    tile[tr + j*16][tc+2] = v.z; tile[tr + j*16][tc+3] = v.w;
  }
  __syncthreads();
  #pragma unroll
  for (int j = 0; j < 4; ++j){
    u16x4 o;
    #pragma unroll
    for (int i = 0; i < 4; ++i) o[i] = f2bf(tile[tc+i][tr + j*16]);
    *(u16x4*)(out + (size_t)(c0 + tr + j*16) * R + r0 + tc) = o;
  }
}

// ---------- fused token+pos embedding -> x fp32, + layer-0 LN1 -> hbuf bf16 (wave per row) ----------
__global__ __launch_bounds__(256) void k_embed_ln(const int* __restrict__ idx,
                                                  const float* __restrict__ te,
                                                  const float* __restrict__ pe,
                                                  const float* __restrict__ g,
                                                  const float* __restrict__ bb,
                                                  float* __restrict__ x, u16* __restrict__ out){
  int row = blockIdx.x * 4 + (threadIdx.x >> 6);
  int lane = threadIdx.x & 63;
  int id = idx[row];
  const float* a = te + (size_t)id * DIM;
  const float* p = pe + (size_t)(row & 1023) * DIM;
  float* xr = x + (size_t)row * DIM;
  float v[12], s = 0.f;
  #pragma unroll
  for (int j = 0; j < 12; ++j){
    int c = j*64 + lane;
    v[j] = a[c] + p[c];
    xr[c] = v[j];
    s += v[j];
  }
  #pragma unroll
  for (int o = 32; o; o >>= 1) s += __shfl_xor(s, o);
  float mu = s * (1.f/768.f);
  float vs = 0.f;
  #pragma unroll
  for (int j = 0; j < 12; ++j){ float d = v[j]-mu; vs += d*d; }
  #pragma unroll
  for (int o = 32; o; o >>= 1) vs += __shfl_xor(vs, o);
  float rs = rsqrtf(vs * (1.f/768.f) + 1e-5f);
  u16* orow = out + (size_t)row * DIM;
  #pragma unroll
  for (int j = 0; j < 12; ++j){
    int c = j*64 + lane;
    orow[c] = f2bf((v[j]-mu)*rs*g[c] + bb[c]);
  }
}

// ---------- layernorm fp32 -> bf16, one wave per row ----------
__global__ __launch_bounds__(256) void k_ln(const float* __restrict__ x, const float* __restrict__ g,
                                            const float* __restrict__ bb, u16* __restrict__ out){
  int row = blockIdx.x * 4 + (threadIdx.x >> 6);
  int lane = threadIdx.x & 63;
  const float* xr = x + (size_t)row * DIM;
  float v[12], s = 0.f;
  #pragma unroll
  for (int j = 0; j < 12; ++j){ v[j] = xr[j*64 + lane]; s += v[j]; }
  #pragma unroll
  for (int o = 32; o; o >>= 1) s += __shfl_xor(s, o);
  float mu = s * (1.f/768.f);
  float vs = 0.f;
  #pragma unroll
  for (int j = 0; j < 12; ++j){ float d = v[j]-mu; vs += d*d; }
  #pragma unroll
  for (int o = 32; o; o >>= 1) vs += __shfl_xor(vs, o);
  float rs = rsqrtf(vs * (1.f/768.f) + 1e-5f);
  u16* orow = out + (size_t)row * DIM;
  #pragma unroll
  for (int j = 0; j < 12; ++j){
    int c = j*64 + lane;
    orow[c] = f2bf((v[j]-mu)*rs*g[c] + bb[c]);
  }
}

// ---------- GEMM: A[M=2048][K] bf16 row-major, BT[N][K] bf16, TMx128 tile, BK=32 ----------
// TM = 128 (wave tile 64x64) or 64 (wave tile 32x64, for small-N GEMMs -> 2x grid).
// TAG distinguishes call sites in rocprof. XCD swizzle + m-fastest grouping; XOR chunk-swizzle LDS.
// EPI: 0 = fp32 store (no bias); 1 = +bias -> bf16, V-slice also written transposed to vt;
//      2 = +bias, gelu -> bf16; 3 = +bias, += fp32 resid
template<int EPI, int TM, int TAG>
__global__ __launch_bounds__(256) void k_gemm(const u16* __restrict__ A, const u16* __restrict__ BT,
                                              const float* __restrict__ bias, void* __restrict__ outp,
                                              u16* __restrict__ vt, int N, int K){
  constexpr int MI  = TM / 32;       // m-fragments per wave
  constexpr int MBC = TT / TM;       // m-blocks per n-panel
  __shared__ __align__(16) u16 Ab[2][TM][32];
  __shared__ __align__(16) u16 Bb[2][128][32];
  int t = threadIdx.x, w = t >> 6, l = t & 63;
  // XCD swizzle: each XCD gets a contiguous wgid chunk; within chunk m varies fastest.
  int cpx = gridDim.x >> 3;               // all grids divisible by 8
  int wgid = (blockIdx.x & 7) * cpx + (blockIdx.x >> 3);
  int m0 = (wgid & (MBC - 1)) * TM;
  int n0 = (wgid / MBC) * 128;
  const u16* Ag = A  + (size_t)m0 * K;
  const u16* Bg = BT + (size_t)n0 * K;
  f32x4 acc[MI][4] = {};
  int NT = K >> 5;
  int lr = l >> 2;                            // staging row within 16-row group
  int cs = (((l & 3) ^ ((l >> 3) & 3)) * 8);  // swizzled source chunk (within 64B line)

  auto stage = [&](int buf, int kt){
    int k0 = kt * 32 + cs;
    int rb = w * 16;
    gload_lds16(Ag + (size_t)(rb + lr) * K + k0,      &Ab[buf][rb][0]);
    if constexpr (TM == 128)
      gload_lds16(Ag + (size_t)(64 + rb + lr) * K + k0, &Ab[buf][64 + rb][0]);
    gload_lds16(Bg + (size_t)(rb + lr) * K + k0,      &Bb[buf][rb][0]);
    gload_lds16(Bg + (size_t)(64 + rb + lr) * K + k0, &Bb[buf][64 + rb][0]);
  };

  stage(0, 0);
  __syncthreads();
  int wm = (w >> 1) * (TM / 2), wn = (w & 1) * 64;
  int ku = l >> 4, r16 = l & 15;
  int sl = (ku ^ ((r16 >> 1) & 3)) * 8;       // swizzled read slot (per-lane constant)
  for (int kt = 0; kt < NT; ++kt){
    int buf = kt & 1;
    if (kt + 1 < NT) stage(buf ^ 1, kt + 1);
    s16x8 af[MI], bfr[4];
    #pragma unroll
    for (int mi = 0; mi < MI; ++mi) af[mi]  = *(const s16x8*)&Ab[buf][wm + mi*16 + r16][sl];
    #pragma unroll
    for (int ni = 0; ni < 4; ++ni)  bfr[ni] = *(const s16x8*)&Bb[buf][wn + ni*16 + r16][sl];
    #pragma unroll
    for (int mi = 0; mi < MI; ++mi)
      #pragma unroll
      for (int ni = 0; ni < 4; ++ni)
        mfma16(acc[mi][ni], af[mi], bfr[ni]);
    __syncthreads();
  }
  asm volatile("s_nop 7\ns_nop 7\ns_nop 7\ns_nop 7");   // MFMA -> VALU hazard
  int rg = l >> 4;
  #pragma unroll
  for (int mi = 0; mi < MI; ++mi){
    #pragma unroll
    for (int ni = 0; ni < 4; ++ni){
      int col = n0 + wn + ni*16 + r16;
      float bv = (EPI != 0) ? bias[col] : 0.f;
      u16x4 vo;
      int rbase = m0 + wm + mi*16 + rg*4;
      #pragma unroll
      for (int r = 0; r < 4; ++r){
        int row = rbase + r;
        float v = acc[mi][ni][r] + bv;
        size_t oi = (size_t)row * N + col;
        if (EPI == 0)      ((float*)outp)[oi] = v;
        else if (EPI == 1){ u16 q = f2bf(v); ((u16*)outp)[oi] = q; vo[r] = q; }
        else if (EPI == 2){ v = 0.5f*v*(1.f + erff(v*0.70710678118f)); ((u16*)outp)[oi] = f2bf(v); }
        else { float* p = (float*)outp + oi; *p += v; }
      }
      if (EPI == 1 && col >= 2*DIM){   // V slice: also write transposed vt[b][h][d][s]
        int hh = (col - 2*DIM) >> 6, dd = (col - 2*DIM) & 63;
        int b  = rbase >> 10, s0 = rbase & 1023;
        *(u16x4*)(vt + ((size_t)(b*12 + hh)*64 + dd)*1024 + s0) = vo;
      }
    }
  }
}

// ---------- flash attention, MFMA 16x16x32; block = 64 q rows (4 waves x 16) ----------
__global__ __launch_bounds__(256) void k_attn(const u16* __restrict__ qkv, const u16* __restrict__ vt,
                                              u16* __restrict__ y){
  int qb = blockIdx.x, h = blockIdx.y, b = blockIdx.z;
  int t = threadIdx.x, wv = t >> 6, l = t & 63;
  int q0 = qb * 64;
  __shared__ __align__(16) u16 Kt[64][72];   // [k][d], +8 pad breaks bank conflicts
  __shared__ __align__(16) u16 Vtl[64][72];  // [d][k]
  __shared__ __align__(16) u16 Pl[4][16][72];
  int colb = l & 15, rowg = (l >> 4) * 4;
  // Q fragments (registers, constant across tiles)
  const u16* qp = qkv + (size_t)(b*1024 + q0 + wv*16 + colb) * D3 + h*64 + (l>>4)*8;
  s16x8 qa0 = *(const s16x8*)qp;
  s16x8 qa1 = *(const s16x8*)(qp + 32);
  f32x4 ao[4] = {};
  float m[4]  = {-1e30f,-1e30f,-1e30f,-1e30f};
  float ls[4] = {0.f,0.f,0.f,0.f};
  const u16* kbase = qkv + (size_t)b*1024*D3 + DIM + h*64;
  const u16* vbase = vt + (size_t)(b*12 + h)*64*1024;
  int kk = t >> 2, cg = (t & 3) * 16;
  int ntiles = qb + 1;
  for (int kt = 0; kt < ntiles; ++kt){
    { // stage K tile [k][d] and V^T tile [d][k]
      const u16* ks = kbase + (size_t)(kt*64 + kk) * D3 + cg;
      *(s16x8*)&Kt[kk][cg]    = *(const s16x8*)ks;
      *(s16x8*)&Kt[kk][cg+8]  = *(const s16x8*)(ks + 8);
      const u16* vs = vbase + (size_t)kk * 1024 + kt*64 + cg;
      *(s16x8*)&Vtl[kk][cg]   = *(const s16x8*)vs;
      *(s16x8*)&Vtl[kk][cg+8] = *(const s16x8*)(vs + 8);
    }
    __syncthreads();
    // QK^T
    f32x4 as[4];
    #pragma unroll
    for (int nf = 0; nf < 4; ++nf){
      as[nf] = 0.f;
      s16x8 b0 = *(const s16x8*)&Kt[nf*16 + colb][(l>>4)*8];
      s16x8 b1 = *(const s16x8*)&Kt[nf*16 + colb][32 + (l>>4)*8];
      mfma16(as[nf], qa0, b0);
      mfma16(as[nf], qa1, b1);
    }
    asm volatile("s_nop 7\ns_nop 7\ns_nop 7");   // MFMA -> VALU hazard
    // mask + online softmax (fp32)
    float sv[4][4];
    int qgb = q0 + wv*16 + rowg;
    #pragma unroll
    for (int nf = 0; nf < 4; ++nf){
      int kglob = kt*64 + nf*16 + colb;
      #pragma unroll
      for (int r = 0; r < 4; ++r){
        float s = as[nf][r] * 0.125f;
        sv[nf][r] = (kglob > qgb + r) ? -1e30f : s;
      }
    }
    float corr[4], rs[4];
    #pragma unroll
    for (int r = 0; r < 4; ++r){
      float v = fmaxf(fmaxf(sv[0][r], sv[1][r]), fmaxf(sv[2][r], sv[3][r]));
      v = fmaxf(v, __shfl_xor(v, 1)); v = fmaxf(v, __shfl_xor(v, 2));
      v = fmaxf(v, __shfl_xor(v, 4)); v = fmaxf(v, __shfl_xor(v, 8));
      float mn = fmaxf(m[r], v);
      corr[r] = __expf(m[r] - mn);
      m[r] = mn;
      rs[r] = 0.f;
    }
    #pragma unroll
    for (int nf = 0; nf < 4; ++nf){
      #pragma unroll
      for (int r = 0; r < 4; ++r){
        float p = __expf(sv[nf][r] - m[r]);
        rs[r] += p;
        Pl[wv][rowg + r][nf*16 + colb] = f2bf(p);
      }
    }
    #pragma unroll
    for (int r = 0; r < 4; ++r){
      float v = rs[r];
      v += __shfl_xor(v, 1); v += __shfl_xor(v, 2); v += __shfl_xor(v, 4); v += __shfl_xor(v, 8);
      ls[r] = ls[r]*corr[r] + v;
    }
    #pragma unroll
    for (int nf = 0; nf < 4; ++nf)
      #pragma unroll
      for (int r = 0; r < 4; ++r)
        ao[nf][r] *= corr[r];
    asm volatile("s_waitcnt lgkmcnt(0)" ::: "memory");   // P writes -> P reads (wave-local)
    // PV
    s16x8 pa0 = *(const s16x8*)&Pl[wv][colb][(l>>4)*8];
    s16x8 pa1 = *(const s16x8*)&Pl[wv][colb][32 + (l>>4)*8];
    #pragma unroll
    for (int nf = 0; nf < 4; ++nf){
      s16x8 v0 = *(const s16x8*)&Vtl[nf*16 + colb][(l>>4)*8];
      s16x8 v1 = *(const s16x8*)&Vtl[nf*16 + colb][32 + (l>>4)*8];
      mfma16(ao[nf], pa0, v0);
      mfma16(ao[nf], pa1, v1);
    }
    __syncthreads();
  }
  asm volatile("s_nop 7\ns_nop 7\ns_nop 7\ns_nop 7");
  #pragma unroll
  for (int nf = 0; nf < 4; ++nf){
    #pragma unroll
    for (int r = 0; r < 4; ++r){
      int qg = q0 + wv*16 + rowg + r;
      int d  = nf*16 + colb;
      y[(size_t)(b*1024 + qg)*DIM + h*64 + d] = f2bf(ao[nf][r] / ls[r]);
    }
  }
}

extern "C" void kernel_launch(void* const* d_in, const int* in_sizes, int n_in,
                              void* d_out, int out_size, void* d_ws, size_t ws_size,
                              hipStream_t stream){
  (void)in_sizes; (void)n_in; (void)out_size; (void)ws_size;
  const int*   idx     = (const int*)  d_in[0];
  const float* tok_emb = (const float*)d_in[1];
  const float* pos_emb = (const float*)d_in[2];
  const float* ln1_g   = (const float*)d_in[3];
  const float* ln1_b   = (const float*)d_in[4];
  const float* qkv_w   = (const float*)d_in[5];
  const float* qkv_b   = (const float*)d_in[6];
  const float* attn_w  = (const float*)d_in[7];
  const float* attn_b  = (const float*)d_in[8];
  const float* ln2_g   = (const float*)d_in[9];
  const float* ln2_b   = (const float*)d_in[10];
  const float* fc_w    = (const float*)d_in[11];
  const float* fc_b    = (const float*)d_in[12];
  const float* mlp_w   = (const float*)d_in[13];
  const float* mlp_b   = (const float*)d_in[14];
  const float* lnf_g   = (const float*)d_in[15];
  const float* lnf_b   = (const float*)d_in[16];

  char* ws = (char*)d_ws;
  size_t off = 0;
  auto take = [&](size_t bytes)->char*{
    char* p = ws + off; off += (bytes + 255) & ~(size_t)255; return p;
  };
  u16*   wqkvT = (u16*)  take((size_t)LAYERS*D3*DIM*2);
  u16*   wattT = (u16*)  take((size_t)LAYERS*DIM*DIM*2);
  u16*   wfcT  = (u16*)  take((size_t)LAYERS*DF*DIM*2);
  u16*   wmlpT = (u16*)  take((size_t)LAYERS*DIM*DF*2);
  u16*   embB  = (u16*)  take((size_t)VOCAB*DIM*2);
  float* x     = (float*)take((size_t)TT*DIM*4);
  u16*   hbuf  = (u16*)  take((size_t)TT*DIM*2);
  u16*   qkvb  = (u16*)  take((size_t)TT*D3*2);
  u16*   yb    = (u16*)  take((size_t)TT*DIM*2);
  u16*   fcb   = (u16*)  take((size_t)TT*DF*2);
  u16*   xfb   = (u16*)  take((size_t)TT*DIM*2);
  u16*   vtb   = (u16*)  take((size_t)2*12*64*1024*2);

  // merged weight prep (bf16 + B^T layout) + tok_emb convert: one dispatch
  k_prep<<<dim3(16368), 256, 0, stream>>>(qkv_w, attn_w, fc_w, mlp_w, tok_emb,
                                          wqkvT, wattT, wfcT, wmlpT, embB);
  // fused embedding + layer-0 LN1
  k_embed_ln<<<TT/4, 256, 0, stream>>>(idx, tok_emb, pos_emb, ln1_g, ln1_b, x, hbuf);

  for (int l = 0; l < LAYERS; ++l){
    if (l > 0)
      k_ln<<<TT/4, 256, 0, stream>>>(x, ln1_g + l*DIM, ln1_b + l*DIM, hbuf);
    k_gemm<1,128,0><<<dim3((TT/128)*(D3/128)), 256, 0, stream>>>(
        hbuf, wqkvT + (size_t)l*D3*DIM, qkv_b + l*D3, qkvb, vtb, D3, DIM);
    k_attn<<<dim3(16, 12, 2), 256, 0, stream>>>(qkvb, vtb, yb);
    k_gemm<3,64,1><<<dim3((TT/64)*(DIM/128)), 256, 0, stream>>>(
        yb, wattT + (size_t)l*DIM*DIM, attn_b + l*DIM, x, nullptr, DIM, DIM);
    k_ln<<<TT/4, 256, 0, stream>>>(x, ln2_g + l*DIM, ln2_b + l*DIM, hbuf);
    k_gemm<2,128,2><<<dim3((TT/128)*(DF/128)), 256, 0, stream>>>(
        hbuf, wfcT + (size_t)l*DF*DIM, fc_b + l*DF, fcb, nullptr, DF, DIM);
    k_gemm<3,64,3><<<dim3((TT/64)*(DIM/128)), 256, 0, stream>>>(
        fcb, wmlpT + (size_t)l*DIM*DF, mlp_b + l*DIM, x, nullptr, DIM, DF);
  }
  k_ln<<<TT/4, 256, 0, stream>>>(x, lnf_g, lnf_b, xfb);
  k_gemm<0,128,4><<<dim3((TT/128)*(VOCAB/128)), 256, 0, stream>>>(
      xfb, embB, nullptr, d_out, nullptr, VOCAB, DIM);
}

// Round 10
// 1367.563 us; speedup vs baseline: 1.0433x; 1.0123x over previous
//
#include <hip/hip_runtime.h>

#define LAYERS 6
#define DIM    768
#define D3     2304
#define DF     3072
#define TT     2048
#define VOCAB  32000

typedef unsigned short u16;
typedef __attribute__((ext_vector_type(4))) float f32x4;
typedef __attribute__((ext_vector_type(8))) short s16x8;
typedef __attribute__((ext_vector_type(4))) unsigned short u16x4;

__device__ __forceinline__ float bf2f(u16 a){
  unsigned int u = ((unsigned int)a) << 16;
  float f; __builtin_memcpy(&f, &u, 4); return f;
}
__device__ __forceinline__ u16 f2bf(float f){
  unsigned int u; __builtin_memcpy(&u, &f, 4);
  u = (u + 0x7fffu + ((u >> 16) & 1u)) >> 16;
  return (u16)u;
}
__device__ __forceinline__ void gload_lds16(const void* g, void* l){
  __builtin_amdgcn_global_load_lds(
      (const __attribute__((address_space(1))) unsigned int*)g,
      (__attribute__((address_space(3))) unsigned int*)l, 16, 0, 0);
}
__device__ __forceinline__ void mfma16(f32x4& d, s16x8 a, s16x8 b){
  asm("v_mfma_f32_16x16x32_bf16 %0, %1, %2, %0" : "+v"(d) : "v"(a), "v"(b));
}

// ---------- merged weight prep: 4 transposes (fp32 [R][C] -> bf16 [C][R]) + tok_emb convert ----------
__global__ __launch_bounds__(256) void k_prep(const float* __restrict__ qkv_w,
                                              const float* __restrict__ attn_w,
                                              const float* __restrict__ fc_w,
                                              const float* __restrict__ mlp_w,
                                              const float* __restrict__ tok_emb,
                                              u16* __restrict__ wqkvT, u16* __restrict__ wattT,
                                              u16* __restrict__ wfcT,  u16* __restrict__ wmlpT,
                                              u16* __restrict__ embB){
  int bid = blockIdx.x;
  if (bid >= 10368){            // tok_emb fp32 -> bf16, 1024 float4 per block (4 sweeps of 256)
    int base = (bid - 10368) * 1024;
    #pragma unroll
    for (int j = 0; j < 4; ++j){
      int i = base + j * 256 + threadIdx.x;
      float4 v = ((const float4*)tok_emb)[i];
      u16x4 o;
      o[0] = f2bf(v.x); o[1] = f2bf(v.y); o[2] = f2bf(v.z); o[3] = f2bf(v.w);
      ((u16x4*)embB)[i] = o;
    }
    return;
  }
  const float* in; u16* out; int R, C, tpl;
  if (bid < 2592)      {             in = qkv_w;  out = wqkvT; R = 768;  C = 2304; tpl = 432; }
  else if (bid < 3456) { bid -= 2592; in = attn_w; out = wattT; R = 768;  C = 768;  tpl = 144; }
  else if (bid < 6912) { bid -= 3456; in = fc_w;   out = wfcT;  R = 768;  C = 3072; tpl = 576; }
  else                 { bid -= 6912; in = mlp_w;  out = wmlpT; R = 3072; C = 768;  tpl = 576; }
  int layer = bid / tpl, rem = bid - layer * tpl;
  int cpt = C >> 6;
  int bx = rem % cpt, by = rem / cpt;
  size_t ls = (size_t)R * C;
  in  += ls * layer;
  out += ls * layer;
  __shared__ float tile[64][65];
  int r0 = by * 64, c0 = bx * 64;
  int t = threadIdx.x;
  int tr = t >> 4, tc = (t & 15) * 4;
  #pragma unroll
  for (int j = 0; j < 4; ++j){
    float4 v = *(const float4*)(in + (size_t)(r0 + tr + j*16) * C + c0 + tc);
    tile[tr + j*16][tc+0] = v.x; tile[tr + j*16][tc+1] = v.y;
    tile[tr + j*16][tc+2] = v.z; tile[tr + j*16][tc+3] = v.w;
  }
  __syncthreads();
  #pragma unroll
  for (int j = 0; j < 4; ++j){
    u16x4 o;
    #pragma unroll
    for (int i = 0; i < 4; ++i) o[i] = f2bf(tile[tc+i][tr + j*16]);
    *(u16x4*)(out + (size_t)(c0 + tr + j*16) * R + r0 + tc) = o;
  }
}

// ---------- fused token+pos embedding -> x fp32, + layer-0 LN1 -> hbuf bf16 (wave per row) ----------
__global__ __launch_bounds__(256) void k_embed_ln(const int* __restrict__ idx,
                                                  const float* __restrict__ te,
                                                  const float* __restrict__ pe,
                                                  const float* __restrict__ g,
                                                  const float* __restrict__ bb,
                                                  float* __restrict__ x, u16* __restrict__ out){
  int row = blockIdx.x * 4 + (threadIdx.x >> 6);
  int lane = threadIdx.x & 63;
  int id = idx[row];
  const float* a = te + (size_t)id * DIM;
  const float* p = pe + (size_t)(row & 1023) * DIM;
  float* xr = x + (size_t)row * DIM;
  float v[12], s = 0.f;
  #pragma unroll
  for (int j = 0; j < 12; ++j){
    int c = j*64 + lane;
    v[j] = a[c] + p[c];
    xr[c] = v[j];
    s += v[j];
  }
  #pragma unroll
  for (int o = 32; o; o >>= 1) s += __shfl_xor(s, o);
  float mu = s * (1.f/768.f);
  float vs = 0.f;
  #pragma unroll
  for (int j = 0; j < 12; ++j){ float d = v[j]-mu; vs += d*d; }
  #pragma unroll
  for (int o = 32; o; o >>= 1) vs += __shfl_xor(vs, o);
  float rs = rsqrtf(vs * (1.f/768.f) + 1e-5f);
  u16* orow = out + (size_t)row * DIM;
  #pragma unroll
  for (int j = 0; j < 12; ++j){
    int c = j*64 + lane;
    orow[c] = f2bf((v[j]-mu)*rs*g[c] + bb[c]);
  }
}

// ---------- layernorm fp32 -> bf16, one wave per row ----------
__global__ __launch_bounds__(256) void k_ln(const float* __restrict__ x, const float* __restrict__ g,
                                            const float* __restrict__ bb, u16* __restrict__ out){
  int row = blockIdx.x * 4 + (threadIdx.x >> 6);
  int lane = threadIdx.x & 63;
  const float* xr = x + (size_t)row * DIM;
  float v[12], s = 0.f;
  #pragma unroll
  for (int j = 0; j < 12; ++j){ v[j] = xr[j*64 + lane]; s += v[j]; }
  #pragma unroll
  for (int o = 32; o; o >>= 1) s += __shfl_xor(s, o);
  float mu = s * (1.f/768.f);
  float vs = 0.f;
  #pragma unroll
  for (int j = 0; j < 12; ++j){ float d = v[j]-mu; vs += d*d; }
  #pragma unroll
  for (int o = 32; o; o >>= 1) vs += __shfl_xor(vs, o);
  float rs = rsqrtf(vs * (1.f/768.f) + 1e-5f);
  u16* orow = out + (size_t)row * DIM;
  #pragma unroll
  for (int j = 0; j < 12; ++j){
    int c = j*64 + lane;
    orow[c] = f2bf((v[j]-mu)*rs*g[c] + bb[c]);
  }
}

// ---------- GEMM: A[M=2048][K] bf16 row-major, BT[N][K] bf16, TMx128 tile, BK=32 ----------
// TM = 128 (wave tile 64x64) or 64 (wave tile 32x64 -> 2x grid for load balance).
// TAG distinguishes call sites in rocprof. XCD swizzle + m-fastest grouping; XOR chunk-swizzle LDS.
// EPI: 0 = fp32 store (no bias); 1 = +bias -> bf16, V-slice also written transposed to vt;
//      2 = +bias, gelu -> bf16; 3 = +bias, += fp32 resid
template<int EPI, int TM, int TAG>
__global__ __launch_bounds__(256) void k_gemm(const u16* __restrict__ A, const u16* __restrict__ BT,
                                              const float* __restrict__ bias, void* __restrict__ outp,
                                              u16* __restrict__ vt, int N, int K){
  constexpr int MI  = TM / 32;       // m-fragments per wave
  constexpr int MBC = TT / TM;       // m-blocks per n-panel
  __shared__ __align__(16) u16 Ab[2][TM][32];
  __shared__ __align__(16) u16 Bb[2][128][32];
  int t = threadIdx.x, w = t >> 6, l = t & 63;
  // XCD swizzle: each XCD gets a contiguous wgid chunk; within chunk m varies fastest.
  int cpx = gridDim.x >> 3;               // all grids divisible by 8
  int wgid = (blockIdx.x & 7) * cpx + (blockIdx.x >> 3);
  int m0 = (wgid & (MBC - 1)) * TM;
  int n0 = (wgid / MBC) * 128;
  const u16* Ag = A  + (size_t)m0 * K;
  const u16* Bg = BT + (size_t)n0 * K;
  f32x4 acc[MI][4] = {};
  int NT = K >> 5;
  int lr = l >> 2;                            // staging row within 16-row group
  int cs = (((l & 3) ^ ((l >> 3) & 3)) * 8);  // swizzled source chunk (within 64B line)

  auto stage = [&](int buf, int kt){
    int k0 = kt * 32 + cs;
    int rb = w * 16;
    gload_lds16(Ag + (size_t)(rb + lr) * K + k0,      &Ab[buf][rb][0]);
    if constexpr (TM == 128)
      gload_lds16(Ag + (size_t)(64 + rb + lr) * K + k0, &Ab[buf][64 + rb][0]);
    gload_lds16(Bg + (size_t)(rb + lr) * K + k0,      &Bb[buf][rb][0]);
    gload_lds16(Bg + (size_t)(64 + rb + lr) * K + k0, &Bb[buf][64 + rb][0]);
  };

  stage(0, 0);
  __syncthreads();
  int wm = (w >> 1) * (TM / 2), wn = (w & 1) * 64;
  int ku = l >> 4, r16 = l & 15;
  int sl = (ku ^ ((r16 >> 1) & 3)) * 8;       // swizzled read slot (per-lane constant)
  for (int kt = 0; kt < NT; ++kt){
    int buf = kt & 1;
    if (kt + 1 < NT) stage(buf ^ 1, kt + 1);
    s16x8 af[MI], bfr[4];
    #pragma unroll
    for (int mi = 0; mi < MI; ++mi) af[mi]  = *(const s16x8*)&Ab[buf][wm + mi*16 + r16][sl];
    #pragma unroll
    for (int ni = 0; ni < 4; ++ni)  bfr[ni] = *(const s16x8*)&Bb[buf][wn + ni*16 + r16][sl];
    #pragma unroll
    for (int mi = 0; mi < MI; ++mi)
      #pragma unroll
      for (int ni = 0; ni < 4; ++ni)
        mfma16(acc[mi][ni], af[mi], bfr[ni]);
    __syncthreads();
  }
  asm volatile("s_nop 7\ns_nop 7\ns_nop 7\ns_nop 7");   // MFMA -> VALU hazard
  int rg = l >> 4;
  #pragma unroll
  for (int mi = 0; mi < MI; ++mi){
    #pragma unroll
    for (int ni = 0; ni < 4; ++ni){
      int col = n0 + wn + ni*16 + r16;
      float bv = (EPI != 0) ? bias[col] : 0.f;
      u16x4 vo;
      int rbase = m0 + wm + mi*16 + rg*4;
      #pragma unroll
      for (int r = 0; r < 4; ++r){
        int row = rbase + r;
        float v = acc[mi][ni][r] + bv;
        size_t oi = (size_t)row * N + col;
        if (EPI == 0)      ((float*)outp)[oi] = v;
        else if (EPI == 1){ u16 q = f2bf(v); ((u16*)outp)[oi] = q; vo[r] = q; }
        else if (EPI == 2){ v = 0.5f*v*(1.f + erff(v*0.70710678118f)); ((u16*)outp)[oi] = f2bf(v); }
        else { float* p = (float*)outp + oi; *p += v; }
      }
      if (EPI == 1 && col >= 2*DIM){   // V slice: also write transposed vt[b][h][d][s]
        int hh = (col - 2*DIM) >> 6, dd = (col - 2*DIM) & 63;
        int b  = rbase >> 10, s0 = rbase & 1023;
        *(u16x4*)(vt + ((size_t)(b*12 + hh)*64 + dd)*1024 + s0) = vo;
      }
    }
  }
}

// ---------- flash attention, MFMA 16x16x32; block = 64 q rows (4 waves x 16) ----------
// (round-8 verified version: staged K/V^T in LDS, barriers)
__global__ __launch_bounds__(256) void k_attn(const u16* __restrict__ qkv, const u16* __restrict__ vt,
                                              u16* __restrict__ y){
  int qb = blockIdx.x, h = blockIdx.y, b = blockIdx.z;
  int t = threadIdx.x, wv = t >> 6, l = t & 63;
  int q0 = qb * 64;
  __shared__ __align__(16) u16 Kt[64][72];   // [k][d], +8 pad breaks bank conflicts
  __shared__ __align__(16) u16 Vtl[64][72];  // [d][k]
  __shared__ __align__(16) u16 Pl[4][16][72];
  int colb = l & 15, rowg = (l >> 4) * 4;
  // Q fragments (registers, constant across tiles)
  const u16* qp = qkv + (size_t)(b*1024 + q0 + wv*16 + colb) * D3 + h*64 + (l>>4)*8;
  s16x8 qa0 = *(const s16x8*)qp;
  s16x8 qa1 = *(const s16x8*)(qp + 32);
  f32x4 ao[4] = {};
  float m[4]  = {-1e30f,-1e30f,-1e30f,-1e30f};
  float ls[4] = {0.f,0.f,0.f,0.f};
  const u16* kbase = qkv + (size_t)b*1024*D3 + DIM + h*64;
  const u16* vbase = vt + (size_t)(b*12 + h)*64*1024;
  int kk = t >> 2, cg = (t & 3) * 16;
  int ntiles = qb + 1;
  for (int kt = 0; kt < ntiles; ++kt){
    { // stage K tile [k][d] and V^T tile [d][k]
      const u16* ks = kbase + (size_t)(kt*64 + kk) * D3 + cg;
      *(s16x8*)&Kt[kk][cg]    = *(const s16x8*)ks;
      *(s16x8*)&Kt[kk][cg+8]  = *(const s16x8*)(ks + 8);
      const u16* vs = vbase + (size_t)kk * 1024 + kt*64 + cg;
      *(s16x8*)&Vtl[kk][cg]   = *(const s16x8*)vs;
      *(s16x8*)&Vtl[kk][cg+8] = *(const s16x8*)(vs + 8);
    }
    __syncthreads();
    // QK^T
    f32x4 as[4];
    #pragma unroll
    for (int nf = 0; nf < 4; ++nf){
      as[nf] = 0.f;
      s16x8 b0 = *(const s16x8*)&Kt[nf*16 + colb][(l>>4)*8];
      s16x8 b1 = *(const s16x8*)&Kt[nf*16 + colb][32 + (l>>4)*8];
      mfma16(as[nf], qa0, b0);
      mfma16(as[nf], qa1, b1);
    }
    asm volatile("s_nop 7\ns_nop 7\ns_nop 7");   // MFMA -> VALU hazard
    // mask + online softmax (fp32)
    float sv[4][4];
    int qgb = q0 + wv*16 + rowg;
    #pragma unroll
    for (int nf = 0; nf < 4; ++nf){
      int kglob = kt*64 + nf*16 + colb;
      #pragma unroll
      for (int r = 0; r < 4; ++r){
        float s = as[nf][r] * 0.125f;
        sv[nf][r] = (kglob > qgb + r) ? -1e30f : s;
      }
    }
    float corr[4], rs[4];
    #pragma unroll
    for (int r = 0; r < 4; ++r){
      float v = fmaxf(fmaxf(sv[0][r], sv[1][r]), fmaxf(sv[2][r], sv[3][r]));
      v = fmaxf(v, __shfl_xor(v, 1)); v = fmaxf(v, __shfl_xor(v, 2));
      v = fmaxf(v, __shfl_xor(v, 4)); v = fmaxf(v, __shfl_xor(v, 8));
      float mn = fmaxf(m[r], v);
      corr[r] = __expf(m[r] - mn);
      m[r] = mn;
      rs[r] = 0.f;
    }
    #pragma unroll
    for (int nf = 0; nf < 4; ++nf){
      #pragma unroll
      for (int r = 0; r < 4; ++r){
        float p = __expf(sv[nf][r] - m[r]);
        rs[r] += p;
        Pl[wv][rowg + r][nf*16 + colb] = f2bf(p);
      }
    }
    #pragma unroll
    for (int r = 0; r < 4; ++r){
      float v = rs[r];
      v += __shfl_xor(v, 1); v += __shfl_xor(v, 2); v += __shfl_xor(v, 4); v += __shfl_xor(v, 8);
      ls[r] = ls[r]*corr[r] + v;
    }
    #pragma unroll
    for (int nf = 0; nf < 4; ++nf)
      #pragma unroll
      for (int r = 0; r < 4; ++r)
        ao[nf][r] *= corr[r];
    asm volatile("s_waitcnt lgkmcnt(0)" ::: "memory");   // P writes -> P reads (wave-local)
    // PV
    s16x8 pa0 = *(const s16x8*)&Pl[wv][colb][(l>>4)*8];
    s16x8 pa1 = *(const s16x8*)&Pl[wv][colb][32 + (l>>4)*8];
    #pragma unroll
    for (int nf = 0; nf < 4; ++nf){
      s16x8 v0 = *(const s16x8*)&Vtl[nf*16 + colb][(l>>4)*8];
      s16x8 v1 = *(const s16x8*)&Vtl[nf*16 + colb][32 + (l>>4)*8];
      mfma16(ao[nf], pa0, v0);
      mfma16(ao[nf], pa1, v1);
    }
    __syncthreads();
  }
  asm volatile("s_nop 7\ns_nop 7\ns_nop 7\ns_nop 7");
  #pragma unroll
  for (int nf = 0; nf < 4; ++nf){
    #pragma unroll
    for (int r = 0; r < 4; ++r){
      int qg = q0 + wv*16 + rowg + r;
      int d  = nf*16 + colb;
      y[(size_t)(b*1024 + qg)*DIM + h*64 + d] = f2bf(ao[nf][r] / ls[r]);
    }
  }
}

extern "C" void kernel_launch(void* const* d_in, const int* in_sizes, int n_in,
                              void* d_out, int out_size, void* d_ws, size_t ws_size,
                              hipStream_t stream){
  (void)in_sizes; (void)n_in; (void)out_size; (void)ws_size;
  const int*   idx     = (const int*)  d_in[0];
  const float* tok_emb = (const float*)d_in[1];
  const float* pos_emb = (const float*)d_in[2];
  const float* ln1_g   = (const float*)d_in[3];
  const float* ln1_b   = (const float*)d_in[4];
  const float* qkv_w   = (const float*)d_in[5];
  const float* qkv_b   = (const float*)d_in[6];
  const float* attn_w  = (const float*)d_in[7];
  const float* attn_b  = (const float*)d_in[8];
  const float* ln2_g   = (const float*)d_in[9];
  const float* ln2_b   = (const float*)d_in[10];
  const float* fc_w    = (const float*)d_in[11];
  const float* fc_b    = (const float*)d_in[12];
  const float* mlp_w   = (const float*)d_in[13];
  const float* mlp_b   = (const float*)d_in[14];
  const float* lnf_g   = (const float*)d_in[15];
  const float* lnf_b   = (const float*)d_in[16];

  char* ws = (char*)d_ws;
  size_t off = 0;
  auto take = [&](size_t bytes)->char*{
    char* p = ws + off; off += (bytes + 255) & ~(size_t)255; return p;
  };
  u16*   wqkvT = (u16*)  take((size_t)LAYERS*D3*DIM*2);
  u16*   wattT = (u16*)  take((size_t)LAYERS*DIM*DIM*2);
  u16*   wfcT  = (u16*)  take((size_t)LAYERS*DF*DIM*2);
  u16*   wmlpT = (u16*)  take((size_t)LAYERS*DIM*DF*2);
  u16*   embB  = (u16*)  take((size_t)VOCAB*DIM*2);
  float* x     = (float*)take((size_t)TT*DIM*4);
  u16*   hbuf  = (u16*)  take((size_t)TT*DIM*2);
  u16*   qkvb  = (u16*)  take((size_t)TT*D3*2);
  u16*   yb    = (u16*)  take((size_t)TT*DIM*2);
  u16*   fcb   = (u16*)  take((size_t)TT*DF*2);
  u16*   xfb   = (u16*)  take((size_t)TT*DIM*2);
  u16*   vtb   = (u16*)  take((size_t)2*12*64*1024*2);

  // merged weight prep (bf16 + B^T layout) + tok_emb convert: one dispatch
  k_prep<<<dim3(16368), 256, 0, stream>>>(qkv_w, attn_w, fc_w, mlp_w, tok_emb,
                                          wqkvT, wattT, wfcT, wmlpT, embB);
  // fused embedding + layer-0 LN1
  k_embed_ln<<<TT/4, 256, 0, stream>>>(idx, tok_emb, pos_emb, ln1_g, ln1_b, x, hbuf);

  for (int l = 0; l < LAYERS; ++l){
    if (l > 0)
      k_ln<<<TT/4, 256, 0, stream>>>(x, ln1_g + l*DIM, ln1_b + l*DIM, hbuf);
    k_gemm<1,64,0><<<dim3((TT/64)*(D3/128)), 256, 0, stream>>>(
        hbuf, wqkvT + (size_t)l*D3*DIM, qkv_b + l*D3, qkvb, vtb, D3, DIM);
    k_attn<<<dim3(16, 12, 2), 256, 0, stream>>>(qkvb, vtb, yb);
    k_gemm<3,64,1><<<dim3((TT/64)*(DIM/128)), 256, 0, stream>>>(
        yb, wattT + (size_t)l*DIM*DIM, attn_b + l*DIM, x, nullptr, DIM, DIM);
    k_ln<<<TT/4, 256, 0, stream>>>(x, ln2_g + l*DIM, ln2_b + l*DIM, hbuf);
    k_gemm<2,64,2><<<dim3((TT/64)*(DF/128)), 256, 0, stream>>>(
        hbuf, wfcT + (size_t)l*DF*DIM, fc_b + l*DF, fcb, nullptr, DF, DIM);
    k_gemm<3,64,3><<<dim3((TT/64)*(DIM/128)), 256, 0, stream>>>(
        fcb, wmlpT + (size_t)l*DIM*DF, mlp_b + l*DIM, x, nullptr, DIM, DF);
  }
  k_ln<<<TT/4, 256, 0, stream>>>(x, lnf_g, lnf_b, xfb);
  // LM head split into two vocab halves (same stride N=VOCAB; frees top-5 slots in rocprof)
  k_gemm<0,128,4><<<dim3((TT/128)*(VOCAB/256)), 256, 0, stream>>>(
      xfb, embB, nullptr, d_out, nullptr, VOCAB, DIM);
  k_gemm<0,128,5><<<dim3((TT/128)*(VOCAB/256)), 256, 0, stream>>>(
      xfb, embB + (size_t)(VOCAB/2)*DIM, nullptr, (float*)d_out + VOCAB/2, nullptr, VOCAB, DIM);
}